// Round 1
// baseline (171319.385 us; speedup 1.0000x reference)
//
#include <hip/hip_runtime.h>
#include <math.h>

#define NB 32
#define NS 512
#define NE 1024
#define NAA 2
#define NH 1024
#define NZ 512
#define NL 64
#define NH3 3072
#define NCQ 2112
#define NCP 1088

// output layout (floats): h_seq, sp, mp, gp, h_seq(dup), sq, mq, gq
static constexpr size_t SZH = (size_t)NB * NS * NH;   // 16777216
static constexpr size_t SZZ = (size_t)NB * NS * NZ;   // 8388608
static constexpr size_t OH1 = 0;
static constexpr size_t OSP = SZH;
static constexpr size_t OMP = OSP + SZZ;
static constexpr size_t OGP = OMP + SZZ;
static constexpr size_t OH2 = OGP + SZZ;              // 41943040
static constexpr size_t OSQ = OH2 + SZH;              // 58720256
static constexpr size_t OMQ = OSQ + SZZ;
static constexpr size_t OGQ = OMQ + SZZ;

static __device__ __forceinline__ float lrelu(float v) { return v >= 0.f ? v : 0.01f * v; }
static __device__ __forceinline__ float sigm(float v)  { return 1.f / (1.f + expf(-v)); }

// Tiled GEMV-batch segment: acc += sum_k src(b,k) * Wrow[k], k in [0, klen).
// Block of NT threads cooperatively stages src into LDS (chunks of 128),
// then each thread accumulates its own (b, col) dot from LDS + global W.
// xl stride 132 floats: 16B-aligned rows; with b on upper lane bits the
// ds_read_b128 per wave hits 8 distinct rows -> banks 4b+k..4b+k+3 disjoint.
template<int NT, typename F>
static __device__ __forceinline__ float seg_accum(float acc, const float* __restrict__ Wrow,
                                                  float (&xl)[NB][132], int klen,
                                                  int b, int tid, F src)
{
  for (int kc = 0; kc < klen; kc += 128) {
    int c2 = klen - kc; if (c2 > 128) c2 = 128;
    const int sh = (c2 == 128) ? 7 : 6;
    const int tot = NB << sh;
    for (int i = tid; i < tot; i += NT) {
      const int bb = i >> sh;
      const int kk = i - (bb << sh);
      xl[bb][kk] = src(bb, kc + kk);
    }
    __syncthreads();
    const float* __restrict__ wp = Wrow + kc;
    float p0 = 0.f, p1 = 0.f, p2 = 0.f, p3 = 0.f;
    #pragma unroll 8
    for (int k = 0; k < c2; k += 4) {
      const float4 w  = *(const float4*)(wp + k);
      const float4 xv = *(const float4*)(&xl[b][k]);
      p0 = fmaf(w.x, xv.x, p0);
      p1 = fmaf(w.y, xv.y, p1);
      p2 = fmaf(w.z, xv.z, p2);
      p3 = fmaf(w.w, xv.w, p3);
    }
    acc += (p0 + p1) + (p2 + p3);
    __syncthreads();
  }
  return acc;
}

// Stage A: x = lrelu(s @ preW^T + preb)  [g<128, 8 cols/WG]
//          gh = h @ Whh^T + bhh          [128<=g<512]
//          la_p, la_q (K=2 action MLPs)  [g==512]
__global__ __launch_bounds__(256) void kA(
    const float* __restrict__ s, const float* __restrict__ h,
    const float* __restrict__ action,
    const float* __restrict__ preW, const float* __restrict__ preb,
    const float* __restrict__ Whh, const float* __restrict__ bhh,
    const float* __restrict__ pactW, const float* __restrict__ pactb,
    const float* __restrict__ qactW, const float* __restrict__ qactb,
    float* __restrict__ x, float* __restrict__ gh,
    float* __restrict__ lap, float* __restrict__ laq, int t)
{
  __shared__ float xl[NB][132];
  const int tid = threadIdx.x;
  const int b = tid >> 3, cl = tid & 7;
  const int g = blockIdx.x;
  if (g < 128) {
    const int col = g * 8 + cl;
    float acc = seg_accum<256>(0.f, preW + (size_t)col * NZ, xl, NZ, b, tid,
                               [&](int bb, int k) { return s[bb * NZ + k]; });
    x[b * NH + col] = lrelu(acc + preb[col]);
  } else if (g < 512) {
    const int col = (g - 128) * 8 + cl;
    float acc = seg_accum<256>(0.f, Whh + (size_t)col * NH, xl, NH, b, tid,
                               [&](int bb, int k) { return h[bb * NH + k]; });
    gh[b * NH3 + col] = acc + bhh[col];
  } else {
    for (int i = tid; i < NB * NL * 2; i += 256) {
      const int which = i >> 11;           // 0 -> prior, 1 -> post
      const int r = i & 2047;
      const int bb = r >> 6, l = r & 63;
      float a0 = 0.f, a1 = 0.f;
      if (t > 0) {
        a0 = action[((size_t)bb * NS + (t - 1)) * NAA + 0];
        a1 = action[((size_t)bb * NS + (t - 1)) * NAA + 1];
      }
      const float* W  = which ? qactW : pactW;
      const float* bi = which ? qactb : pactb;
      const float v = lrelu(a0 * W[l * NAA + 0] + a1 * W[l * NAA + 1] + bi[l]);
      (which ? laq : lap)[bb * NL + l] = v;
    }
  }
}

// Stage B: gi = x @ Wih^T + bih for a 4-col tile of all 3 gates (12 dots),
// then GRU gates fused via small LDS exchange; writes h in place + h_seq x2.
__global__ __launch_bounds__(384) void kB(
    const float* __restrict__ x, const float* __restrict__ Wih, const float* __restrict__ bih,
    const float* __restrict__ gh, float* __restrict__ h,
    float* __restrict__ out, int t)
{
  __shared__ float xl[NB][132];
  __shared__ float gib[NB][12];
  const int tid = threadIdx.x;
  const int b = tid & 31, slot = tid >> 5;       // slot 0..11
  const int gate = slot >> 2;
  const int c = blockIdx.x * 4 + (slot & 3);     // h-col 0..1023
  const int colw = gate * NH + c;                // row of Wih / gi col
  float acc = seg_accum<384>(0.f, Wih + (size_t)colw * NH, xl, NH, b, tid,
                             [&](int bb, int k) { return x[bb * NH + k]; });
  gib[b][slot] = acc + bih[colw];
  __syncthreads();
  if (slot < 4) {
    const float ir = gib[b][slot], iz = gib[b][slot + 4], inn = gib[b][slot + 8];
    const float hr = gh[b * NH3 + c];
    const float hz = gh[b * NH3 + NH + c];
    const float hn = gh[b * NH3 + 2 * NH + c];
    const float r = sigm(ir + hr);
    const float z = sigm(iz + hz);
    const float n = tanhf(inn + r * hn);
    const float hp = h[b * NH + c];
    const float hnew = (1.f - z) * n + z * hp;
    h[b * NH + c] = hnew;
    const size_t o = ((size_t)b * NS + t) * NH + c;
    out[OH1 + o] = hnew;
    out[OH2 + o] = hnew;
  }
}

// Stage C: hmid_q = lrelu([h, e_t, la_q] @ W1q^T + b1q)  [g<264]
//          hmid_p = lrelu([h, la_p] @ W1p^T + b1p)       [else]
__global__ __launch_bounds__(256) void kC(
    const float* __restrict__ h, const float* __restrict__ emb,
    const float* __restrict__ lap, const float* __restrict__ laq,
    const float* __restrict__ W1q, const float* __restrict__ b1q,
    const float* __restrict__ W1p, const float* __restrict__ b1p,
    float* __restrict__ hmq, float* __restrict__ hmp, int t)
{
  __shared__ float xl[NB][132];
  const int tid = threadIdx.x;
  const int b = tid >> 3, cl = tid & 7;
  const int g = blockIdx.x;
  auto hs = [&](int bb, int k) { return h[bb * NH + k]; };
  if (g < 264) {
    const int col = g * 8 + cl;
    const float* Wr = W1q + (size_t)col * NCQ;
    float acc = seg_accum<256>(0.f, Wr, xl, NH, b, tid, hs);
    acc = seg_accum<256>(acc, Wr + NH, xl, NE, b, tid,
                         [&](int bb, int k) { return emb[((size_t)bb * NS + t) * NE + k]; });
    acc = seg_accum<256>(acc, Wr + NH + NE, xl, NL, b, tid,
                         [&](int bb, int k) { return laq[bb * NL + k]; });
    hmq[b * NCQ + col] = lrelu(acc + b1q[col]);
  } else {
    const int col = (g - 264) * 8 + cl;
    const float* Wr = W1p + (size_t)col * NCP;
    float acc = seg_accum<256>(0.f, Wr, xl, NH, b, tid, hs);
    acc = seg_accum<256>(acc, Wr + NH, xl, NL, b, tid,
                         [&](int bb, int k) { return lap[bb * NL + k]; });
    hmp[b * NCP + col] = lrelu(acc + b1p[col]);
  }
}

// Stage D: ml = hmid @ W2^T + b2; mu/sigma/sample; write outputs; samp_q -> s.
// 4 z-values per WG; slots 0..3 compute mu cols, 4..7 compute ls cols.
__global__ __launch_bounds__(256) void kD(
    const float* __restrict__ hmq, const float* __restrict__ hmp,
    const float* __restrict__ W2q, const float* __restrict__ b2q,
    const float* __restrict__ W2p, const float* __restrict__ b2p,
    const float* __restrict__ npost, const float* __restrict__ nprior,
    float* __restrict__ s, float* __restrict__ out, int t)
{
  __shared__ float xl[NB][132];
  __shared__ float lsb[NB][4];
  const int tid = threadIdx.x;
  const int b = tid >> 3, cl = tid & 7;
  const int g = blockIdx.x;
  if (g < 128) {
    const int zc = g * 4 + (cl & 3);
    const bool isls = cl >= 4;
    const int col = isls ? (NZ + zc) : zc;
    float acc = seg_accum<256>(0.f, W2q + (size_t)col * NCQ, xl, NCQ, b, tid,
                               [&](int bb, int k) { return hmq[bb * NCQ + k]; });
    acc += b2q[col];
    if (isls) lsb[b][cl & 3] = acc;
    __syncthreads();
    if (!isls) {
      const float mu = acc;
      const float ls = lsb[b][cl & 3];
      const float sg = 2.f * sigm(0.5f * ls) + 0.1f;
      const size_t o = ((size_t)b * NS + t) * NZ + zc;
      const float smp = mu + sg * npost[o];
      out[OSQ + o] = smp;
      out[OMQ + o] = mu;
      out[OGQ + o] = sg;
      s[b * NZ + zc] = smp;
    }
  } else {
    const int zc = (g - 128) * 4 + (cl & 3);
    const bool isls = cl >= 4;
    const int col = isls ? (NZ + zc) : zc;
    float acc = seg_accum<256>(0.f, W2p + (size_t)col * NCP, xl, NCP, b, tid,
                               [&](int bb, int k) { return hmp[bb * NCP + k]; });
    acc += b2p[col];
    if (isls) lsb[b][cl & 3] = acc;
    __syncthreads();
    if (!isls) {
      const float mu = acc;
      const float ls = lsb[b][cl & 3];
      const float sg = 2.f * sigm(0.5f * ls) + 0.1f;
      const size_t o = ((size_t)b * NS + t) * NZ + zc;
      const float smp = mu + sg * nprior[o];
      out[OSP + o] = smp;
      out[OMP + o] = mu;
      out[OGP + o] = sg;
    }
  }
}

extern "C" void kernel_launch(void* const* d_in, const int* in_sizes, int n_in,
                              void* d_out, int out_size, void* d_ws, size_t ws_size,
                              hipStream_t stream)
{
  const float* emb   = (const float*)d_in[0];
  const float* act   = (const float*)d_in[1];
  const float* npr   = (const float*)d_in[2];
  const float* npo   = (const float*)d_in[3];
  const float* preW  = (const float*)d_in[4];
  const float* preb  = (const float*)d_in[5];
  const float* Wih   = (const float*)d_in[6];
  const float* Whh   = (const float*)d_in[7];
  const float* bih   = (const float*)d_in[8];
  const float* bhh   = (const float*)d_in[9];
  const float* qactW = (const float*)d_in[10];
  const float* qactb = (const float*)d_in[11];
  const float* pactW = (const float*)d_in[12];
  const float* pactb = (const float*)d_in[13];
  const float* W1q   = (const float*)d_in[14];
  const float* b1q   = (const float*)d_in[15];
  const float* W2q   = (const float*)d_in[16];
  const float* b2q   = (const float*)d_in[17];
  const float* W1p   = (const float*)d_in[18];
  const float* b1p   = (const float*)d_in[19];
  const float* W2p   = (const float*)d_in[20];
  const float* b2p   = (const float*)d_in[21];

  float* out = (float*)d_out;
  float* ws  = (float*)d_ws;
  // ws layout (floats)
  float* s   = ws;            // 16384
  float* h   = ws + 16384;    // 32768
  float* x   = ws + 49152;    // 32768
  float* gh  = ws + 81920;    // 98304
  float* lap = ws + 180224;   // 2048
  float* laq = ws + 182272;   // 2048
  float* hmp = ws + 184320;   // 34816
  float* hmq = ws + 219136;   // 67584  -> total 286720 floats (~1.1 MB)

  // zero initial state (s, h contiguous at ws start); ws is poisoned each call
  hipMemsetAsync(ws, 0, 49152 * sizeof(float), stream);

  for (int t = 0; t < NS; ++t) {
    kA<<<513, 256, 0, stream>>>(s, h, act, preW, preb, Whh, bhh,
                                pactW, pactb, qactW, qactb, x, gh, lap, laq, t);
    kB<<<256, 384, 0, stream>>>(x, Wih, bih, gh, h, out, t);
    kC<<<400, 256, 0, stream>>>(h, emb, lap, laq, W1q, b1q, W1p, b1p, hmq, hmp, t);
    kD<<<256, 256, 0, stream>>>(hmq, hmp, W2q, b2q, W2p, b2p, npo, npr, s, out, t);
  }
}

// Round 2
// 78021.387 us; speedup vs baseline: 2.1958x; 2.1958x over previous
//
#include <hip/hip_runtime.h>
#include <math.h>

#define NB 32
#define NS 512
#define NE 1024
#define NAA 2
#define NH 1024
#define NZ 512
#define NL 64
#define NH3 3072
#define NCQ 2112
#define NCP 1088

// output layout (floats): h_seq, sp, mp, gp, h_seq(dup), sq, mq, gq
static constexpr size_t SZH = (size_t)NB * NS * NH;
static constexpr size_t SZZ = (size_t)NB * NS * NZ;
static constexpr size_t OH1 = 0;
static constexpr size_t OSP = SZH;
static constexpr size_t OMP = OSP + SZZ;
static constexpr size_t OGP = OMP + SZZ;
static constexpr size_t OH2 = OGP + SZZ;
static constexpr size_t OSQ = OH2 + SZH;
static constexpr size_t OMQ = OSQ + SZZ;
static constexpr size_t OGQ = OMQ + SZZ;

static __device__ __forceinline__ float lrelu(float v) { return v >= 0.f ? v : 0.01f * v; }
static __device__ __forceinline__ float sigm(float v)  { return 1.f / (1.f + expf(-v)); }

// ---------------------------------------------------------------------------
// kA: x = lrelu(s @ preW^T + preb)   [g <  64, 16 cols/block]
//     gh = h @ Whh^T + bhh           [64 <= g < 256, 16 cols/block]
//     la_p, la_q action MLPs (K=2)   [g == 256]
// Lane map (16-col): col = lane&15, bgrp = lane>>4, b = bgrp*8 + j (j<8).
// K split 8 ways across the block's 8 waves; LDS reduce at end.
// ---------------------------------------------------------------------------
__global__ __launch_bounds__(512) void kA(
    const float* __restrict__ s, const float* __restrict__ h,
    const float* __restrict__ action,
    const float* __restrict__ preW, const float* __restrict__ preb,
    const float* __restrict__ Whh, const float* __restrict__ bhh,
    const float* __restrict__ pactW, const float* __restrict__ pactb,
    const float* __restrict__ qactW, const float* __restrict__ qactb,
    float* __restrict__ x, float* __restrict__ gh,
    float* __restrict__ lap, float* __restrict__ laq, int t)
{
  __shared__ float part[8][544];   // [wid][b*17 + col], padded stride 17
  const int tid = threadIdx.x;
  const int g = blockIdx.x;
  if (g < 256) {
    const int lane = tid & 63, wid = tid >> 6;
    const int col = lane & 15, b0 = (lane >> 4) * 8;
    const bool isX = g < 64;
    const float* W    = isX ? preW : Whh;
    const float* xsrc = isX ? s : h;
    const float* bias = isX ? preb : bhh;
    const int K    = isX ? NZ : NH;
    const int colg = (isX ? g : g - 64) * 16;
    const int slice = K >> 3;
    const int k0 = wid * slice, k1 = k0 + slice;
    const float* __restrict__ Wrow = W + (size_t)(colg + col) * K;
    const float* __restrict__ xp = xsrc + (size_t)b0 * K;
    float acc[8][4];
    #pragma unroll
    for (int j = 0; j < 8; ++j) { acc[j][0]=0.f; acc[j][1]=0.f; acc[j][2]=0.f; acc[j][3]=0.f; }
    #pragma unroll 2
    for (int k = k0; k < k1; k += 4) {
      const float4 w = *(const float4*)(Wrow + k);
      #pragma unroll
      for (int j = 0; j < 8; ++j) {
        const float4 xv = *(const float4*)(xp + (size_t)j * K + k);
        acc[j][0] = fmaf(w.x, xv.x, acc[j][0]);
        acc[j][1] = fmaf(w.y, xv.y, acc[j][1]);
        acc[j][2] = fmaf(w.z, xv.z, acc[j][2]);
        acc[j][3] = fmaf(w.w, xv.w, acc[j][3]);
      }
    }
    #pragma unroll
    for (int j = 0; j < 8; ++j)
      part[wid][(b0 + j) * 17 + col] = (acc[j][0] + acc[j][1]) + (acc[j][2] + acc[j][3]);
    __syncthreads();
    const int b = tid >> 4, c = tid & 15;   // 512 outputs, one per thread
    float v = 0.f;
    #pragma unroll
    for (int w = 0; w < 8; ++w) v += part[w][b * 17 + c];
    v += bias[colg + c];
    if (isX) x[b * NH + colg + c] = lrelu(v);
    else     gh[b * NH3 + colg + c] = v;
  } else {
    // action MLPs: 2 * 32 * 64 = 4096 outputs
    for (int i = tid; i < NB * NL * 2; i += 512) {
      const int which = i >> 11;            // 0 prior, 1 post
      const int r = i & 2047;
      const int bb = r >> 6, l = r & 63;
      float a0 = 0.f, a1 = 0.f;
      if (t > 0) {
        a0 = action[((size_t)bb * NS + (t - 1)) * NAA + 0];
        a1 = action[((size_t)bb * NS + (t - 1)) * NAA + 1];
      }
      const float* W  = which ? qactW : pactW;
      const float* bi = which ? qactb : pactb;
      const float v = lrelu(a0 * W[l * NAA + 0] + a1 * W[l * NAA + 1] + bi[l]);
      (which ? laq : lap)[bb * NL + l] = v;
    }
  }
}

// ---------------------------------------------------------------------------
// kB: gi = x @ Wih^T + bih for 8 h-cols x 3 gates, then full GRU combine.
// Lane map (8-col): col = lane&7, bgrp = lane>>3, b = bgrp*4 + j (j<4).
// ---------------------------------------------------------------------------
__global__ __launch_bounds__(512) void kB(
    const float* __restrict__ x, const float* __restrict__ Wih, const float* __restrict__ bih,
    const float* __restrict__ gh, float* __restrict__ h,
    float* __restrict__ out, int t)
{
  __shared__ float part[3][8][288];  // [gate][wid][b*9 + col]
  const int tid = threadIdx.x;
  const int lane = tid & 63, wid = tid >> 6;
  const int col = lane & 7, b0 = (lane >> 3) * 4;
  const int g = blockIdx.x;
  const int c = g * 8 + col;
  const int k0 = wid * 128, k1 = k0 + 128;
  const float* __restrict__ W0 = Wih + (size_t)c * NH;
  const float* __restrict__ W1 = W0 + (size_t)NH * NH;
  const float* __restrict__ W2 = W1 + (size_t)NH * NH;
  const float* __restrict__ xp = x + (size_t)b0 * NH;
  float a0[4][4], a1[4][4], a2[4][4];
  #pragma unroll
  for (int j = 0; j < 4; ++j)
    #pragma unroll
    for (int q = 0; q < 4; ++q) { a0[j][q]=0.f; a1[j][q]=0.f; a2[j][q]=0.f; }
  #pragma unroll 2
  for (int k = k0; k < k1; k += 4) {
    const float4 w0 = *(const float4*)(W0 + k);
    const float4 w1 = *(const float4*)(W1 + k);
    const float4 w2 = *(const float4*)(W2 + k);
    #pragma unroll
    for (int j = 0; j < 4; ++j) {
      const float4 xv = *(const float4*)(xp + (size_t)j * NH + k);
      a0[j][0] = fmaf(w0.x, xv.x, a0[j][0]);
      a0[j][1] = fmaf(w0.y, xv.y, a0[j][1]);
      a0[j][2] = fmaf(w0.z, xv.z, a0[j][2]);
      a0[j][3] = fmaf(w0.w, xv.w, a0[j][3]);
      a1[j][0] = fmaf(w1.x, xv.x, a1[j][0]);
      a1[j][1] = fmaf(w1.y, xv.y, a1[j][1]);
      a1[j][2] = fmaf(w1.z, xv.z, a1[j][2]);
      a1[j][3] = fmaf(w1.w, xv.w, a1[j][3]);
      a2[j][0] = fmaf(w2.x, xv.x, a2[j][0]);
      a2[j][1] = fmaf(w2.y, xv.y, a2[j][1]);
      a2[j][2] = fmaf(w2.z, xv.z, a2[j][2]);
      a2[j][3] = fmaf(w2.w, xv.w, a2[j][3]);
    }
  }
  #pragma unroll
  for (int j = 0; j < 4; ++j) {
    part[0][wid][(b0 + j) * 9 + col] = (a0[j][0] + a0[j][1]) + (a0[j][2] + a0[j][3]);
    part[1][wid][(b0 + j) * 9 + col] = (a1[j][0] + a1[j][1]) + (a1[j][2] + a1[j][3]);
    part[2][wid][(b0 + j) * 9 + col] = (a2[j][0] + a2[j][1]) + (a2[j][2] + a2[j][3]);
  }
  __syncthreads();
  if (tid < 256) {
    const int b = tid >> 3, cc = tid & 7;
    const int cg = g * 8 + cc;
    float ir = 0.f, iz = 0.f, inn = 0.f;
    #pragma unroll
    for (int w = 0; w < 8; ++w) {
      ir  += part[0][w][b * 9 + cc];
      iz  += part[1][w][b * 9 + cc];
      inn += part[2][w][b * 9 + cc];
    }
    ir += bih[cg]; iz += bih[NH + cg]; inn += bih[2 * NH + cg];
    const float hr = gh[b * NH3 + cg];
    const float hz = gh[b * NH3 + NH + cg];
    const float hn = gh[b * NH3 + 2 * NH + cg];
    const float r = sigm(ir + hr);
    const float z = sigm(iz + hz);
    const float n = tanhf(inn + r * hn);
    const float hp = h[b * NH + cg];
    const float hnew = (1.f - z) * n + z * hp;
    h[b * NH + cg] = hnew;
    const size_t o = ((size_t)b * NS + t) * NH + cg;
    out[OH1 + o] = hnew;
    out[OH2 + o] = hnew;
  }
}

// ---------------------------------------------------------------------------
// kC: hmid_q = lrelu([h, e_t, la_q] @ W1q^T + b1q)  [g < 132]
//     hmid_p = lrelu([h, la_p] @ W1p^T + b1p)       [g >= 132]
// 16 cols/block; concat handled by per-segment sub-loops (branch-free inner).
// ---------------------------------------------------------------------------
__global__ __launch_bounds__(512) void kC(
    const float* __restrict__ h, const float* __restrict__ emb,
    const float* __restrict__ lap, const float* __restrict__ laq,
    const float* __restrict__ W1q, const float* __restrict__ b1q,
    const float* __restrict__ W1p, const float* __restrict__ b1p,
    float* __restrict__ hmq, float* __restrict__ hmp, int t)
{
  __shared__ float part[8][544];
  const int tid = threadIdx.x;
  const int lane = tid & 63, wid = tid >> 6;
  const int col = lane & 15, b0 = (lane >> 4) * 8;
  const int g = blockIdx.x;
  const bool isQ = g < 132;
  const int colg = (isQ ? g : g - 132) * 16;
  const int K = isQ ? NCQ : NCP;
  const float* __restrict__ Wr = (isQ ? W1q : W1p) + (size_t)(colg + col) * K;
  const int slice = K >> 3;
  const int k0 = wid * slice, k1 = k0 + slice;
  float acc[8][4];
  #pragma unroll
  for (int j = 0; j < 8; ++j) { acc[j][0]=0.f; acc[j][1]=0.f; acc[j][2]=0.f; acc[j][3]=0.f; }

  auto run = [&](int sb, int se, const float* __restrict__ arr, int st) {
    int ka = k0 > sb ? k0 : sb;
    int kb = k1 < se ? k1 : se;
    #pragma unroll 2
    for (int k = ka; k < kb; k += 4) {
      const float4 w = *(const float4*)(Wr + k);
      #pragma unroll
      for (int j = 0; j < 8; ++j) {
        const float4 xv = *(const float4*)(arr + (size_t)(b0 + j) * st + (k - sb));
        acc[j][0] = fmaf(w.x, xv.x, acc[j][0]);
        acc[j][1] = fmaf(w.y, xv.y, acc[j][1]);
        acc[j][2] = fmaf(w.z, xv.z, acc[j][2]);
        acc[j][3] = fmaf(w.w, xv.w, acc[j][3]);
      }
    }
  };
  run(0, NH, h, NH);
  if (isQ) {
    run(NH, NH + NE, emb + (size_t)t * NE, NS * NE);
    run(NH + NE, NCQ, laq, NL);
  } else {
    run(NH, NCP, lap, NL);
  }
  #pragma unroll
  for (int j = 0; j < 8; ++j)
    part[wid][(b0 + j) * 17 + col] = (acc[j][0] + acc[j][1]) + (acc[j][2] + acc[j][3]);
  __syncthreads();
  const int b = tid >> 4, c = tid & 15;
  float v = 0.f;
  #pragma unroll
  for (int w = 0; w < 8; ++w) v += part[w][b * 17 + c];
  v += (isQ ? b1q : b1p)[colg + c];
  v = lrelu(v);
  if (isQ) hmq[b * NCQ + colg + c] = v;
  else     hmp[b * NCP + colg + c] = v;
}

// ---------------------------------------------------------------------------
// kD: ml = hmid @ W2^T + b2; mu/sigma/sample; writes outputs (+ s for next t).
// 8 cols/block = 4 mu rows + 4 ls rows (paired so the epilogue is local).
// ---------------------------------------------------------------------------
__global__ __launch_bounds__(512) void kD(
    const float* __restrict__ hmq, const float* __restrict__ hmp,
    const float* __restrict__ W2q, const float* __restrict__ b2q,
    const float* __restrict__ W2p, const float* __restrict__ b2p,
    const float* __restrict__ npost, const float* __restrict__ nprior,
    float* __restrict__ s, float* __restrict__ out, int t)
{
  __shared__ float part[8][288];
  __shared__ float red[288];
  const int tid = threadIdx.x;
  const int lane = tid & 63, wid = tid >> 6;
  const int col = lane & 7, b0 = (lane >> 3) * 4;
  const int g = blockIdx.x;
  const bool isQ = g < 128;
  const int gg = isQ ? g : g - 128;
  const int K = isQ ? NCQ : NCP;
  const float* __restrict__ hm = isQ ? hmq : hmp;
  const int row = (col < 4) ? gg * 4 + col : NZ + gg * 4 + (col - 4);
  const float* __restrict__ Wr = (isQ ? W2q : W2p) + (size_t)row * K;
  const int slice = K >> 3;
  const int k0 = wid * slice, k1 = k0 + slice;
  float acc[4][4];
  #pragma unroll
  for (int j = 0; j < 4; ++j) { acc[j][0]=0.f; acc[j][1]=0.f; acc[j][2]=0.f; acc[j][3]=0.f; }
  #pragma unroll 2
  for (int k = k0; k < k1; k += 4) {
    const float4 w = *(const float4*)(Wr + k);
    #pragma unroll
    for (int j = 0; j < 4; ++j) {
      const float4 xv = *(const float4*)(hm + (size_t)(b0 + j) * K + k);
      acc[j][0] = fmaf(w.x, xv.x, acc[j][0]);
      acc[j][1] = fmaf(w.y, xv.y, acc[j][1]);
      acc[j][2] = fmaf(w.z, xv.z, acc[j][2]);
      acc[j][3] = fmaf(w.w, xv.w, acc[j][3]);
    }
  }
  #pragma unroll
  for (int j = 0; j < 4; ++j)
    part[wid][(b0 + j) * 9 + col] = (acc[j][0] + acc[j][1]) + (acc[j][2] + acc[j][3]);
  __syncthreads();
  if (tid < 256) {
    const int b = tid >> 3, cc = tid & 7;
    const int rw = (cc < 4) ? gg * 4 + cc : NZ + gg * 4 + (cc - 4);
    float v = 0.f;
    #pragma unroll
    for (int w = 0; w < 8; ++w) v += part[w][b * 9 + cc];
    v += (isQ ? b2q : b2p)[rw];
    red[b * 9 + cc] = v;
  }
  __syncthreads();
  if (tid < 256) {
    const int b = tid >> 3, cc = tid & 7;
    if (cc < 4) {
      const float mu = red[b * 9 + cc];
      const float ls = red[b * 9 + cc + 4];
      const float sg = 2.f * sigm(0.5f * ls) + 0.1f;
      const int zc = gg * 4 + cc;
      const size_t o = ((size_t)b * NS + t) * NZ + zc;
      const float nz = isQ ? npost[o] : nprior[o];
      const float smp = mu + sg * nz;
      if (isQ) {
        out[OSQ + o] = smp;
        out[OMQ + o] = mu;
        out[OGQ + o] = sg;
        s[b * NZ + zc] = smp;
      } else {
        out[OSP + o] = smp;
        out[OMP + o] = mu;
        out[OGP + o] = sg;
      }
    }
  }
}

extern "C" void kernel_launch(void* const* d_in, const int* in_sizes, int n_in,
                              void* d_out, int out_size, void* d_ws, size_t ws_size,
                              hipStream_t stream)
{
  const float* emb   = (const float*)d_in[0];
  const float* act   = (const float*)d_in[1];
  const float* npr   = (const float*)d_in[2];
  const float* npo   = (const float*)d_in[3];
  const float* preW  = (const float*)d_in[4];
  const float* preb  = (const float*)d_in[5];
  const float* Wih   = (const float*)d_in[6];
  const float* Whh   = (const float*)d_in[7];
  const float* bih   = (const float*)d_in[8];
  const float* bhh   = (const float*)d_in[9];
  const float* qactW = (const float*)d_in[10];
  const float* qactb = (const float*)d_in[11];
  const float* pactW = (const float*)d_in[12];
  const float* pactb = (const float*)d_in[13];
  const float* W1q   = (const float*)d_in[14];
  const float* b1q   = (const float*)d_in[15];
  const float* W2q   = (const float*)d_in[16];
  const float* b2q   = (const float*)d_in[17];
  const float* W1p   = (const float*)d_in[18];
  const float* b1p   = (const float*)d_in[19];
  const float* W2p   = (const float*)d_in[20];
  const float* b2p   = (const float*)d_in[21];

  float* out = (float*)d_out;
  float* ws  = (float*)d_ws;
  float* s   = ws;            // 16384
  float* h   = ws + 16384;    // 32768
  float* x   = ws + 49152;    // 32768
  float* gh  = ws + 81920;    // 98304
  float* lap = ws + 180224;   // 2048
  float* laq = ws + 182272;   // 2048
  float* hmp = ws + 184320;   // 34816
  float* hmq = ws + 219136;   // 67584

  hipMemsetAsync(ws, 0, 49152 * sizeof(float), stream);

  for (int t = 0; t < NS; ++t) {
    kA<<<257, 512, 0, stream>>>(s, h, act, preW, preb, Whh, bhh,
                                pactW, pactb, qactW, qactb, x, gh, lap, laq, t);
    kB<<<128, 512, 0, stream>>>(x, Wih, bih, gh, h, out, t);
    kC<<<200, 512, 0, stream>>>(h, emb, lap, laq, W1q, b1q, W1p, b1p, hmq, hmp, t);
    kD<<<256, 512, 0, stream>>>(hmq, hmp, W2q, b2q, W2p, b2p, npo, npr, s, out, t);
  }
}